// Round 4
// baseline (344.925 us; speedup 1.0000x reference)
//
#include <hip/hip_runtime.h>
#include <math.h>

typedef __bf16 bf16x8 __attribute__((ext_vector_type(8)));
typedef float f32x4 __attribute__((ext_vector_type(4)));

// ---------------- weight conversion: fp32 -> bf16 frag-major in d_ws ----------
// Frag (kt,nt) = 32x16 block of B; lane L holds B[kt*32+(L>>4)*8+j][nt*16+(L&15)],
// j=0..7 -> one 16B chunk at L*16. Offsets (bf16 units): L1@0 (96x256, 48 frags),
// L2@24576 (256x128, 64), L3@57344 (128x64, 16), L4@65536 (64x128, 16; N 101->128 pad).
// Params packed LINEAR f32 at bf16-offset 73728:
//   0..255 b1 | 256..511 g1 | 512..767 be1 | 768..895 b2 | 896..1023 g2
//   1024..1151 be2 | 1152..1215 b3 | 1216..1279 g3 | 1280..1343 be3
//   1344..1471 b4 (pad 0) | 1472..1599 qsup (pad 0).  Total ws: 153856 B.
__global__ void conv_weights(const float* __restrict__ W1, const float* __restrict__ W2,
                             const float* __restrict__ W3, const float* __restrict__ W4,
                             const float* __restrict__ b1, const float* __restrict__ g1, const float* __restrict__ be1,
                             const float* __restrict__ b2, const float* __restrict__ g2, const float* __restrict__ be2,
                             const float* __restrict__ b3, const float* __restrict__ g3, const float* __restrict__ be3,
                             const float* __restrict__ b4, const float* __restrict__ qsup,
                             __bf16* __restrict__ ws)
{
  if (blockIdx.x == 36) {
    float* Pp = (float*)(ws + 73728);
    const int t = threadIdx.x;
    Pp[t]       = b1[t];
    Pp[256 + t] = g1[t];
    Pp[512 + t] = be1[t];
    if (t < 128) {
      Pp[768 + t]  = b2[t];
      Pp[896 + t]  = g2[t];
      Pp[1024 + t] = be2[t];
      Pp[1344 + t] = (t < 101) ? b4[t]   : 0.f;
      Pp[1472 + t] = (t < 101) ? qsup[t] : 0.f;
    }
    if (t < 64) {
      Pp[1152 + t] = b3[t];
      Pp[1216 + t] = g3[t];
      Pp[1280 + t] = be3[t];
    }
    return;
  }
  const int f = blockIdx.x * 4 + (threadIdx.x >> 6);
  const int lane = threadIdx.x & 63;
  int f0, ntot, Ksrc, Nsrc, off;
  const float* W;
  if (f < 48)       { f0 = f;       ntot = 16; Ksrc = 80;  Nsrc = 256; W = W1; off = 0; }
  else if (f < 112) { f0 = f - 48;  ntot = 8;  Ksrc = 256; Nsrc = 128; W = W2; off = 24576; }
  else if (f < 128) { f0 = f - 112; ntot = 4;  Ksrc = 128; Nsrc = 64;  W = W3; off = 57344; }
  else              { f0 = f - 128; ntot = 8;  Ksrc = 64;  Nsrc = 101; W = W4; off = 65536; }
  const int kt = f0 / ntot, nt = f0 % ntot;
  const int q = lane >> 4, c = lane & 15;
  const int n = nt * 16 + c;
  bf16x8 v;
#pragma unroll
  for (int j = 0; j < 8; ++j) {
    const int k = kt * 32 + q * 8 + j;
    const float x = (k < Ksrc && n < Nsrc) ? W[k * Nsrc + n] : 0.f;
    v[j] = (__bf16)x;
  }
  ((bf16x8*)(ws + off))[f0 * 64 + lane] = v;
}

// ---------------- fused forward: code-size-minimized (front-end theory) -------
// MFMA structure unchanged; LN/SiLU epilogues + softmax/projection converted
// from fully-unrolled straight-line code to ROLLED loops fed from an LDS f32
// scratch dump of the accumulators. Static code ~26KB -> ~13KB.
//
// Per-wave LDS layout (floats, stride 4240):
//   scr  [0,    2048)  f32 scratch (transposed [col][row] accumulator dumps)
//   h    [2048, 4160)  h1 [16][264] bf16 (2112 f); h2 [16][136] / h3 [16][72] overlay
//   muL  [4160, 4176)  rsL [4176, 4192)   (L1-L3; OUTSIDE h1's range — R3 bug fix)
//   proj [2624, 4240)  [16][101] (L4 only; overlays dead h1 tail + dead muL/rsL;
//                       h3 [2048,2624) stays live and disjoint)
// Block = 4*4240*4 = 67840 B -> 2 blocks/CU (8 waves/CU).

__global__ __launch_bounds__(256, 2)
void sacq_wave(const float* __restrict__ obs,  const float* __restrict__ act,
               const float* __restrict__ rew,  const float* __restrict__ boot,
               const float* __restrict__ disc, const float* __restrict__ qsup,
               const float* __restrict__ b1, const float* __restrict__ g1, const float* __restrict__ be1,
               const float* __restrict__ b2, const float* __restrict__ g2, const float* __restrict__ be2,
               const float* __restrict__ b3, const float* __restrict__ g3, const float* __restrict__ be3,
               const float* __restrict__ b4,
               const __bf16* __restrict__ ws,
               float* __restrict__ out)
{
  __shared__ float sm[16960];
  const int t = threadIdx.x;
  const int wv = t >> 6, lane = t & 63;
  const int q = lane >> 4, c = lane & 15;
  float* smw = sm + wv * 4240;
  float* scr = smw;                        // [0,2048) f32 scratch
  __bf16* h = (__bf16*)(smw + 2048);       // h1/h2/h3 overlay
  float* muL = smw + 4160;                 // [16] row means (L1-L3)
  float* rsL = smw + 4176;                 // [16] row rstds
  float* proj = smw + 2624;                // [16][101] (L4 only)
  const int row0w = blockIdx.x * 64 + wv * 16;
  const bf16x8* wsf = (const bf16x8*)ws;
  const float* Pp = (const float*)(const void*)(ws + 73728);
  const int lq = lane >> 2;                // rolled-pass col-within-16
  const int lr = (lane & 3) * 4;           // rolled-pass base row (0,4,8,12)

  // ================= Layer 1: x[16x80] @ W1 -> 256, LN+SiLU =================
  f32x4 acc1[16];
  {
    bf16x8 A1[3];
    const float4* ob4 = (const float4*)(obs + (size_t)(row0w + c) * 60);
    const float4* ac4 = (const float4*)(act + (size_t)(row0w + c) * 20);
#pragma unroll
    for (int kt = 0; kt < 3; ++kt) {
      const int k0 = kt * 32 + q * 8;
      float v[8];
      if (k0 < 56) {
        const float4 a = ob4[k0 / 4], b = ob4[k0 / 4 + 1];
        v[0]=a.x; v[1]=a.y; v[2]=a.z; v[3]=a.w; v[4]=b.x; v[5]=b.y; v[6]=b.z; v[7]=b.w;
      } else if (k0 == 56) {
        const float4 a = ob4[14], b = ac4[0];
        v[0]=a.x; v[1]=a.y; v[2]=a.z; v[3]=a.w; v[4]=b.x; v[5]=b.y; v[6]=b.z; v[7]=b.w;
      } else if (k0 < 80) {
        const float4 a = ac4[(k0 - 60) / 4], b = ac4[(k0 - 60) / 4 + 1];
        v[0]=a.x; v[1]=a.y; v[2]=a.z; v[3]=a.w; v[4]=b.x; v[5]=b.y; v[6]=b.z; v[7]=b.w;
      } else {
#pragma unroll
        for (int j = 0; j < 8; ++j) v[j] = 0.f;
      }
#pragma unroll
      for (int j = 0; j < 8; ++j) A1[kt][j] = (__bf16)v[j];
    }
#pragma unroll
    for (int nt = 0; nt < 16; ++nt) {
      const float bb = Pp[nt * 16 + c];
      f32x4 vv = {bb, bb, bb, bb};
      acc1[nt] = vv;
    }
#pragma unroll
    for (int ch = 0; ch < 4; ++ch) {
      bf16x8 Bb[3][4];
#pragma unroll
      for (int kt = 0; kt < 3; ++kt)
#pragma unroll
        for (int j = 0; j < 4; ++j)
          Bb[kt][j] = wsf[(kt * 16 + ch * 4 + j) * 64 + lane];
#pragma unroll
      for (int kt = 0; kt < 3; ++kt)
#pragma unroll
        for (int j = 0; j < 4; ++j)
          acc1[ch * 4 + j] = __builtin_amdgcn_mfma_f32_16x16x32_bf16(A1[kt], Bb[kt][j], acc1[ch * 4 + j], 0, 0, 0);
    }
    // stats (exact f32, static)
    float s[4] = {0.f,0.f,0.f,0.f}, s2[4] = {0.f,0.f,0.f,0.f};
#pragma unroll
    for (int nt = 0; nt < 16; ++nt)
#pragma unroll
      for (int r = 0; r < 4; ++r) { const float v = acc1[nt][r]; s[r] += v; s2[r] += v * v; }
#pragma unroll
    for (int r = 0; r < 4; ++r) {
      s[r] += __shfl_xor(s[r], 1); s2[r] += __shfl_xor(s2[r], 1);
      s[r] += __shfl_xor(s[r], 2); s2[r] += __shfl_xor(s2[r], 2);
      s[r] += __shfl_xor(s[r], 4); s2[r] += __shfl_xor(s2[r], 4);
      s[r] += __shfl_xor(s[r], 8); s2[r] += __shfl_xor(s2[r], 8);
      const float m = s[r] * (1.f / 256.f);
      const float rv = rsqrtf(s2[r] * (1.f / 256.f) - m * m + 1e-5f);
      if (c == 0) { muL[4 * q + r] = m; rsL[4 * q + r] = rv; }
    }
    // two halves: dump 8 accs transposed [colh][row], rolled apply
#pragma unroll
    for (int hh = 0; hh < 2; ++hh) {
#pragma unroll
      for (int ntl = 0; ntl < 8; ++ntl)
        *(f32x4*)(scr + (ntl * 16 + c) * 16 + 4 * q) = acc1[hh * 8 + ntl];
#pragma unroll 1
      for (int it = 0; it < 8; ++it) {
        const int colh = it * 16 + lq, col = hh * 128 + colh;
        const f32x4 v  = *(const f32x4*)(scr + colh * 16 + lr);
        const f32x4 m  = *(const f32x4*)(muL + lr);
        const f32x4 rv = *(const f32x4*)(rsL + lr);
        const float gg = Pp[256 + col], bb = Pp[512 + col];
#pragma unroll
        for (int j = 0; j < 4; ++j) {
          float x = (v[j] - m[j]) * rv[j] * gg + bb;
          x = x * __builtin_amdgcn_rcpf(1.f + __expf(-x));
          h[(lr + j) * 264 + col] = (__bf16)x;
        }
      }
    }
  }

  // ================= Layer 2: 256 -> 128, LN+SiLU ===========================
  {
    f32x4 acc2[8];
#pragma unroll
    for (int nt = 0; nt < 8; ++nt) {
      const float bb = Pp[768 + nt * 16 + c];
      f32x4 vv = {bb, bb, bb, bb};
      acc2[nt] = vv;
    }
    bf16x8 B2[3][8];
#pragma unroll
    for (int nt = 0; nt < 8; ++nt) B2[0][nt] = wsf[3072 + (0 * 8 + nt) * 64 + lane];
#pragma unroll
    for (int nt = 0; nt < 8; ++nt) B2[1][nt] = wsf[3072 + (1 * 8 + nt) * 64 + lane];
#pragma unroll
    for (int kt = 0; kt < 8; ++kt) {
      if (kt + 2 < 8) {
#pragma unroll
        for (int nt = 0; nt < 8; ++nt)
          B2[(kt + 2) % 3][nt] = wsf[3072 + ((kt + 2) * 8 + nt) * 64 + lane];
      }
      const bf16x8 A2 = *(const bf16x8*)(h + c * 264 + kt * 32 + q * 8);
#pragma unroll
      for (int nt = 0; nt < 8; ++nt)
        acc2[nt] = __builtin_amdgcn_mfma_f32_16x16x32_bf16(A2, B2[kt % 3][nt], acc2[nt], 0, 0, 0);
    }
    float s[4] = {0.f,0.f,0.f,0.f}, s2[4] = {0.f,0.f,0.f,0.f};
#pragma unroll
    for (int nt = 0; nt < 8; ++nt)
#pragma unroll
      for (int r = 0; r < 4; ++r) { const float v = acc2[nt][r]; s[r] += v; s2[r] += v * v; }
#pragma unroll
    for (int r = 0; r < 4; ++r) {
      s[r] += __shfl_xor(s[r], 1); s2[r] += __shfl_xor(s2[r], 1);
      s[r] += __shfl_xor(s[r], 2); s2[r] += __shfl_xor(s2[r], 2);
      s[r] += __shfl_xor(s[r], 4); s2[r] += __shfl_xor(s2[r], 4);
      s[r] += __shfl_xor(s[r], 8); s2[r] += __shfl_xor(s2[r], 8);
      const float m = s[r] * (1.f / 128.f);
      const float rv = rsqrtf(s2[r] * (1.f / 128.f) - m * m + 1e-5f);
      if (c == 0) { muL[4 * q + r] = m; rsL[4 * q + r] = rv; }
    }
#pragma unroll
    for (int nt = 0; nt < 8; ++nt)
      *(f32x4*)(scr + (nt * 16 + c) * 16 + 4 * q) = acc2[nt];
#pragma unroll 1
    for (int it = 0; it < 8; ++it) {
      const int col = it * 16 + lq;
      const f32x4 v  = *(const f32x4*)(scr + col * 16 + lr);
      const f32x4 m  = *(const f32x4*)(muL + lr);
      const f32x4 rv = *(const f32x4*)(rsL + lr);
      const float gg = Pp[896 + col], bb = Pp[1024 + col];
#pragma unroll
      for (int j = 0; j < 4; ++j) {
        float x = (v[j] - m[j]) * rv[j] * gg + bb;
        x = x * __builtin_amdgcn_rcpf(1.f + __expf(-x));
        h[(lr + j) * 136 + col] = (__bf16)x;
      }
    }
  }

  // ================= Layer 3: 128 -> 64, LN+SiLU ============================
  {
    bf16x8 B3[4][4];
#pragma unroll
    for (int kt = 0; kt < 4; ++kt)
#pragma unroll
      for (int nt = 0; nt < 4; ++nt)
        B3[kt][nt] = wsf[7168 + (kt * 4 + nt) * 64 + lane];
    f32x4 acc3[4];
#pragma unroll
    for (int nt = 0; nt < 4; ++nt) {
      const float bb = Pp[1152 + nt * 16 + c];
      f32x4 vv = {bb, bb, bb, bb};
      acc3[nt] = vv;
    }
#pragma unroll
    for (int kt = 0; kt < 4; ++kt) {
      const bf16x8 A3 = *(const bf16x8*)(h + c * 136 + kt * 32 + q * 8);
#pragma unroll
      for (int nt = 0; nt < 4; ++nt)
        acc3[nt] = __builtin_amdgcn_mfma_f32_16x16x32_bf16(A3, B3[kt][nt], acc3[nt], 0, 0, 0);
    }
    float s[4] = {0.f,0.f,0.f,0.f}, s2[4] = {0.f,0.f,0.f,0.f};
#pragma unroll
    for (int nt = 0; nt < 4; ++nt)
#pragma unroll
      for (int r = 0; r < 4; ++r) { const float v = acc3[nt][r]; s[r] += v; s2[r] += v * v; }
#pragma unroll
    for (int r = 0; r < 4; ++r) {
      s[r] += __shfl_xor(s[r], 1); s2[r] += __shfl_xor(s2[r], 1);
      s[r] += __shfl_xor(s[r], 2); s2[r] += __shfl_xor(s2[r], 2);
      s[r] += __shfl_xor(s[r], 4); s2[r] += __shfl_xor(s2[r], 4);
      s[r] += __shfl_xor(s[r], 8); s2[r] += __shfl_xor(s2[r], 8);
      const float m = s[r] * (1.f / 64.f);
      const float rv = rsqrtf(s2[r] * (1.f / 64.f) - m * m + 1e-5f);
      if (c == 0) { muL[4 * q + r] = m; rsL[4 * q + r] = rv; }
    }
#pragma unroll
    for (int nt = 0; nt < 4; ++nt)
      *(f32x4*)(scr + (nt * 16 + c) * 16 + 4 * q) = acc3[nt];
#pragma unroll 1
    for (int it = 0; it < 4; ++it) {
      const int col = it * 16 + lq;
      const f32x4 v  = *(const f32x4*)(scr + col * 16 + lr);
      const f32x4 m  = *(const f32x4*)(muL + lr);
      const f32x4 rv = *(const f32x4*)(rsL + lr);
      const float gg = Pp[1216 + col], bb = Pp[1280 + col];
#pragma unroll
      for (int j = 0; j < 4; ++j) {
        float x = (v[j] - m[j]) * rv[j] * gg + bb;
        x = x * __builtin_amdgcn_rcpf(1.f + __expf(-x));
        h[(lr + j) * 72 + col] = (__bf16)x;
      }
    }
  }

  // ================= Layer 4 (101 cols) + softmax + projection ===============
  {
    bf16x8 B4[2][7];
#pragma unroll
    for (int kt = 0; kt < 2; ++kt)
#pragma unroll
      for (int nt = 0; nt < 7; ++nt)
        B4[kt][nt] = wsf[8192 + (kt * 8 + nt) * 64 + lane];
    bf16x8 A4f[2];
#pragma unroll
    for (int kt = 0; kt < 2; ++kt)
      A4f[kt] = *(const bf16x8*)(h + c * 72 + kt * 32 + q * 8);
    f32x4 a4[7];
#pragma unroll
    for (int nt = 0; nt < 7; ++nt) {
      const float bb = Pp[1344 + nt * 16 + c];
      f32x4 vv = {bb, bb, bb, bb};
      a4[nt] = vv;
    }
#pragma unroll
    for (int kt = 0; kt < 2; ++kt) {
#pragma unroll
      for (int nt = 0; nt < 7; ++nt)
        a4[nt] = __builtin_amdgcn_mfma_f32_16x16x32_bf16(A4f[kt], B4[kt][nt], a4[nt], 0, 0, 0);
    }
    // dump logits transposed [col][row] (cols >=101 masked below)
#pragma unroll
    for (int nt = 0; nt < 7; ++nt)
      *(f32x4*)(scr + (nt * 16 + c) * 16 + 4 * q) = a4[nt];

    // Fence, then zero proj (proj overlays dead h1 tail + dead muL/rsL; the
    // A4f reads above cover live h3; keep stores ordered after them).
    asm volatile("" ::: "memory");
    {
      f32x4 z = {0.f, 0.f, 0.f, 0.f};
      f32x4* p4 = (f32x4*)proj;
      for (int i = lane; i < 404; i += 64) p4[i] = z;
    }

    // pass A0: per-row max (rolled)
    float mx[4] = {-3.4e38f, -3.4e38f, -3.4e38f, -3.4e38f};
#pragma unroll 1
    for (int it = 0; it < 7; ++it) {
      const int col = it * 16 + lq;
      const f32x4 v = *(const f32x4*)(scr + col * 16 + lr);
      if (col < 101) {
#pragma unroll
        for (int j = 0; j < 4; ++j) mx[j] = fmaxf(mx[j], v[j]);
      }
    }
#pragma unroll
    for (int j = 0; j < 4; ++j) {
      mx[j] = fmaxf(mx[j], __shfl_xor(mx[j], 4));
      mx[j] = fmaxf(mx[j], __shfl_xor(mx[j], 8));
      mx[j] = fmaxf(mx[j], __shfl_xor(mx[j], 16));
      mx[j] = fmaxf(mx[j], __shfl_xor(mx[j], 32));
    }
    // pass A: per-row sum of exp
    float sp[4] = {0.f, 0.f, 0.f, 0.f};
#pragma unroll 1
    for (int it = 0; it < 7; ++it) {
      const int col = it * 16 + lq;
      const f32x4 v = *(const f32x4*)(scr + col * 16 + lr);
      const bool ok = col < 101;
#pragma unroll
      for (int j = 0; j < 4; ++j) sp[j] += ok ? __expf(v[j] - mx[j]) : 0.f;
    }
    float inv[4];
#pragma unroll
    for (int j = 0; j < 4; ++j) {
      float x = sp[j];
      x += __shfl_xor(x, 4);
      x += __shfl_xor(x, 8);
      x += __shfl_xor(x, 16);
      x += __shfl_xor(x, 32);
      inv[j] = __builtin_amdgcn_rcpf(x);
    }

    const f32x4 rw4 = *(const f32x4*)(rew  + row0w + lr);
    const f32x4 bo4 = *(const f32x4*)(boot + row0w + lr);
    const f32x4 di4 = *(const f32x4*)(disc + row0w + lr);
    float bd[4];
#pragma unroll
    for (int j = 0; j < 4; ++j) bd[j] = bo4[j] * di4[j];

    // pass B: categorical projection via wave-private LDS atomics
#pragma unroll 1
    for (int it = 0; it < 7; ++it) {
      const int col = it * 16 + lq;
      if (col < 101) {
        const float qsv = Pp[1472 + col];
        const f32x4 v = *(const f32x4*)(scr + col * 16 + lr);
#pragma unroll
        for (int j = 0; j < 4; ++j) {
          const float p = __expf(v[j] - mx[j]) * inv[j];
          float tz = rw4[j] + bd[j] * qsv;
          tz = fminf(fmaxf(tz, -10.f), 10.f);
          const float b_ = (tz + 10.f) * 5.f;
          const float fl = floorf(b_), cl = ceilf(b_);
          int li = (int)fl, ui = (int)cl;
          if (ui == li) { if (li > 0) --li; else ++ui; }
          const int rb = (lr + j) * 101;
          atomicAdd(&proj[rb + li], p * ((float)ui - b_));
          atomicAdd(&proj[rb + ui], p * (b_ - (float)li));
        }
      }
    }
  }

  // ---- coalesced float4 writeout of this wave's 16x101 block
  {
    const f32x4* p4 = (const f32x4*)proj;
    f32x4* o4 = (f32x4*)(out + (size_t)row0w * 101);
    for (int i = lane; i < 404; i += 64) o4[i] = p4[i];
  }
}

extern "C" void kernel_launch(void* const* d_in, const int* in_sizes, int n_in,
                              void* d_out, int out_size, void* d_ws, size_t ws_size,
                              hipStream_t stream)
{
  const int B = in_sizes[2];  // rewards: B elements
  __bf16* ws = (__bf16*)d_ws; // 153856 B used

  conv_weights<<<dim3(37), dim3(256), 0, stream>>>(
      (const float*)d_in[6],  (const float*)d_in[10], (const float*)d_in[14],
      (const float*)d_in[18],
      (const float*)d_in[7],  (const float*)d_in[8],  (const float*)d_in[9],
      (const float*)d_in[11], (const float*)d_in[12], (const float*)d_in[13],
      (const float*)d_in[15], (const float*)d_in[16], (const float*)d_in[17],
      (const float*)d_in[19], (const float*)d_in[5],  ws);

  sacq_wave<<<dim3(B / 64), dim3(256), 0, stream>>>(
      (const float*)d_in[0],  (const float*)d_in[1],  (const float*)d_in[2],
      (const float*)d_in[3],  (const float*)d_in[4],  (const float*)d_in[5],
      (const float*)d_in[7],  (const float*)d_in[8],  (const float*)d_in[9],
      (const float*)d_in[11], (const float*)d_in[12], (const float*)d_in[13],
      (const float*)d_in[15], (const float*)d_in[16], (const float*)d_in[17],
      (const float*)d_in[19], ws, (float*)d_out);
}

// Round 5
// 332.688 us; speedup vs baseline: 1.0368x; 1.0368x over previous
//
#include <hip/hip_runtime.h>
#include <math.h>

typedef __bf16 bf16x8 __attribute__((ext_vector_type(8)));
typedef float f32x4 __attribute__((ext_vector_type(4)));

// ---------------- weight conversion: fp32 -> bf16 frag-major in d_ws ----------
// Frag (kt,nt) = 32x16 block of B; lane L holds B[kt*32+(L>>4)*8+j][nt*16+(L&15)],
// j=0..7 -> one 16B chunk at L*16. Offsets (bf16 units): L1@0 (96x256, 48 frags),
// L2@24576 (256x128, 64), L3@57344 (128x64, 16), L4@65536 (64x128, 16; N 101->128 pad).
// Params packed LINEAR f32 at bf16-offset 73728:
//   0..255 b1 | 256..511 g1 | 512..767 be1 | 768..895 b2 | 896..1023 g2
//   1024..1151 be2 | 1152..1215 b3 | 1216..1279 g3 | 1280..1343 be3
//   1344..1471 b4 (pad 0) | 1472..1599 qsup (pad 0).  Total ws: 153856 B.
__global__ void conv_weights(const float* __restrict__ W1, const float* __restrict__ W2,
                             const float* __restrict__ W3, const float* __restrict__ W4,
                             const float* __restrict__ b1, const float* __restrict__ g1, const float* __restrict__ be1,
                             const float* __restrict__ b2, const float* __restrict__ g2, const float* __restrict__ be2,
                             const float* __restrict__ b3, const float* __restrict__ g3, const float* __restrict__ be3,
                             const float* __restrict__ b4, const float* __restrict__ qsup,
                             __bf16* __restrict__ ws)
{
  if (blockIdx.x == 36) {
    float* Pp = (float*)(ws + 73728);
    const int t = threadIdx.x;
    Pp[t]       = b1[t];
    Pp[256 + t] = g1[t];
    Pp[512 + t] = be1[t];
    if (t < 128) {
      Pp[768 + t]  = b2[t];
      Pp[896 + t]  = g2[t];
      Pp[1024 + t] = be2[t];
      Pp[1344 + t] = (t < 101) ? b4[t]   : 0.f;
      Pp[1472 + t] = (t < 101) ? qsup[t] : 0.f;
    }
    if (t < 64) {
      Pp[1152 + t] = b3[t];
      Pp[1216 + t] = g3[t];
      Pp[1280 + t] = be3[t];
    }
    return;
  }
  const int f = blockIdx.x * 4 + (threadIdx.x >> 6);
  const int lane = threadIdx.x & 63;
  int f0, ntot, Ksrc, Nsrc, off;
  const float* W;
  if (f < 48)       { f0 = f;       ntot = 16; Ksrc = 80;  Nsrc = 256; W = W1; off = 0; }
  else if (f < 112) { f0 = f - 48;  ntot = 8;  Ksrc = 256; Nsrc = 128; W = W2; off = 24576; }
  else if (f < 128) { f0 = f - 112; ntot = 4;  Ksrc = 128; Nsrc = 64;  W = W3; off = 57344; }
  else              { f0 = f - 128; ntot = 8;  Ksrc = 64;  Nsrc = 101; W = W4; off = 65536; }
  const int kt = f0 / ntot, nt = f0 % ntot;
  const int q = lane >> 4, c = lane & 15;
  const int n = nt * 16 + c;
  bf16x8 v;
#pragma unroll
  for (int j = 0; j < 8; ++j) {
    const int k = kt * 32 + q * 8 + j;
    const float x = (k < Ksrc && n < Nsrc) ? W[k * Nsrc + n] : 0.f;
    v[j] = (__bf16)x;
  }
  ((bf16x8*)(ws + off))[f0 * 64 + lane] = v;
}

// ---------------- fused forward: 32 rows/wave (2 row-tiles), direct epilogues -
// THIS ROUND: each wave owns 32 rows (two 16-row MFMA row-tiles). The 142
// weight-fragment loads are traversed once per 32 rows (was per 16), and every
// phase carries TWO independent row-tile dependency chains -> 2x in-wave ILP
// at the same resident-wave count (occupancy was proven non-binding R0-R4).
// Epilogues are the proven R1/R2 direct-register form (R4 scr machinery gone).
//
// Per-wave LDS (floats, stride 4384):
//   h1 [32][264] bf16  = floats [0,4224)   (h2 [32][136], h3 [32][72] overlay;
//      layer-k writes ordered after layer-(k-1) reads: alias-conservative
//      compiler order + in-order per-wave DS)
//   proj [32][101]     = floats [1152,4384)  (L4 only; h3 [0,1152) disjoint)
// Block = 4*4384*4 = 70144 B -> 2 blocks/CU. Grid B/128 = 1024.

__global__ __launch_bounds__(256, 2)
void sacq_wave(const float* __restrict__ obs,  const float* __restrict__ act,
               const float* __restrict__ rew,  const float* __restrict__ boot,
               const float* __restrict__ disc, const float* __restrict__ qsup,
               const float* __restrict__ b1, const float* __restrict__ g1, const float* __restrict__ be1,
               const float* __restrict__ b2, const float* __restrict__ g2, const float* __restrict__ be2,
               const float* __restrict__ b3, const float* __restrict__ g3, const float* __restrict__ be3,
               const float* __restrict__ b4,
               const __bf16* __restrict__ ws,
               float* __restrict__ out)
{
  __shared__ float sm[17536];
  const int t = threadIdx.x;
  const int wv = t >> 6, lane = t & 63;
  const int q = lane >> 4, c = lane & 15;
  float* smw = sm + wv * 4384;
  __bf16* h = (__bf16*)smw;               // h1/h2/h3 overlay
  float* proj = smw + 1152;               // [32][101] (L4 only)
  const int row0w = blockIdx.x * 128 + wv * 32;
  const bf16x8* wsf = (const bf16x8*)ws;
  const float* Pp = (const float*)(const void*)(ws + 73728);

  // ================= Layer 1: x[32x80] @ W1 -> 256, LN+SiLU =================
  f32x4 acc1[2][16];
  {
    bf16x8 A1[2][3];
#pragma unroll
    for (int rt = 0; rt < 2; ++rt) {
      const float4* ob4 = (const float4*)(obs + (size_t)(row0w + rt * 16 + c) * 60);
      const float4* ac4 = (const float4*)(act + (size_t)(row0w + rt * 16 + c) * 20);
#pragma unroll
      for (int kt = 0; kt < 3; ++kt) {
        const int k0 = kt * 32 + q * 8;
        float v[8];
        if (k0 < 56) {
          const float4 a = ob4[k0 / 4], b = ob4[k0 / 4 + 1];
          v[0]=a.x; v[1]=a.y; v[2]=a.z; v[3]=a.w; v[4]=b.x; v[5]=b.y; v[6]=b.z; v[7]=b.w;
        } else if (k0 == 56) {
          const float4 a = ob4[14], b = ac4[0];
          v[0]=a.x; v[1]=a.y; v[2]=a.z; v[3]=a.w; v[4]=b.x; v[5]=b.y; v[6]=b.z; v[7]=b.w;
        } else if (k0 < 80) {
          const float4 a = ac4[(k0 - 60) / 4], b = ac4[(k0 - 60) / 4 + 1];
          v[0]=a.x; v[1]=a.y; v[2]=a.z; v[3]=a.w; v[4]=b.x; v[5]=b.y; v[6]=b.z; v[7]=b.w;
        } else {
#pragma unroll
          for (int j = 0; j < 8; ++j) v[j] = 0.f;
        }
#pragma unroll
        for (int j = 0; j < 8; ++j) A1[rt][kt][j] = (__bf16)v[j];
      }
    }
#pragma unroll
    for (int nt = 0; nt < 16; ++nt) {
      const float bb = Pp[nt * 16 + c];
      f32x4 vv = {bb, bb, bb, bb};
      acc1[0][nt] = vv;
      acc1[1][nt] = vv;
    }
    // 4 chunks of 4 ntiles; each chunk: 12 frag loads, then 24 MFMAs (2 row-tiles)
#pragma unroll
    for (int ch = 0; ch < 4; ++ch) {
      bf16x8 Bb[3][4];
#pragma unroll
      for (int kt = 0; kt < 3; ++kt)
#pragma unroll
        for (int j = 0; j < 4; ++j)
          Bb[kt][j] = wsf[(kt * 16 + ch * 4 + j) * 64 + lane];
#pragma unroll
      for (int kt = 0; kt < 3; ++kt)
#pragma unroll
        for (int j = 0; j < 4; ++j)
#pragma unroll
          for (int rt = 0; rt < 2; ++rt)
            acc1[rt][ch * 4 + j] = __builtin_amdgcn_mfma_f32_16x16x32_bf16(A1[rt][kt], Bb[kt][j], acc1[rt][ch * 4 + j], 0, 0, 0);
    }
#pragma unroll
    for (int rt = 0; rt < 2; ++rt) {
      float s[4] = {0.f,0.f,0.f,0.f}, s2[4] = {0.f,0.f,0.f,0.f};
#pragma unroll
      for (int nt = 0; nt < 16; ++nt)
#pragma unroll
        for (int r = 0; r < 4; ++r) { const float v = acc1[rt][nt][r]; s[r] += v; s2[r] += v * v; }
      float mu[4], rs[4];
#pragma unroll
      for (int r = 0; r < 4; ++r) {
        s[r] += __shfl_xor(s[r], 1); s2[r] += __shfl_xor(s2[r], 1);
        s[r] += __shfl_xor(s[r], 2); s2[r] += __shfl_xor(s2[r], 2);
        s[r] += __shfl_xor(s[r], 4); s2[r] += __shfl_xor(s2[r], 4);
        s[r] += __shfl_xor(s[r], 8); s2[r] += __shfl_xor(s2[r], 8);
        const float m = s[r] * (1.f / 256.f);
        mu[r] = m;
        rs[r] = rsqrtf(s2[r] * (1.f / 256.f) - m * m + 1e-5f);
      }
#pragma unroll
      for (int nt = 0; nt < 16; ++nt) {
        const int col = nt * 16 + c;
        const float gg = Pp[256 + col], bb = Pp[512 + col];
#pragma unroll
        for (int r = 0; r < 4; ++r) {
          float v = (acc1[rt][nt][r] - mu[r]) * rs[r] * gg + bb;
          v = v * __builtin_amdgcn_rcpf(1.f + __expf(-v));
          h[(rt * 16 + 4 * q + r) * 264 + col] = (__bf16)v;
        }
      }
    }
  }

  // ================= Layer 2: 256 -> 128, LN+SiLU (depth-1 kt prefetch) ======
  {
    f32x4 acc2[2][8];
#pragma unroll
    for (int nt = 0; nt < 8; ++nt) {
      const float bb = Pp[768 + nt * 16 + c];
      f32x4 vv = {bb, bb, bb, bb};
      acc2[0][nt] = vv;
      acc2[1][nt] = vv;
    }
    bf16x8 B2[2][8];
#pragma unroll
    for (int nt = 0; nt < 8; ++nt) B2[0][nt] = wsf[3072 + nt * 64 + lane];
#pragma unroll
    for (int kt = 0; kt < 8; ++kt) {
      if (kt + 1 < 8) {
#pragma unroll
        for (int nt = 0; nt < 8; ++nt)
          B2[(kt + 1) & 1][nt] = wsf[3072 + ((kt + 1) * 8 + nt) * 64 + lane];
      }
      bf16x8 A2r[2];
#pragma unroll
      for (int rt = 0; rt < 2; ++rt)
        A2r[rt] = *(const bf16x8*)(h + (rt * 16 + c) * 264 + kt * 32 + q * 8);
#pragma unroll
      for (int nt = 0; nt < 8; ++nt)
#pragma unroll
        for (int rt = 0; rt < 2; ++rt)
          acc2[rt][nt] = __builtin_amdgcn_mfma_f32_16x16x32_bf16(A2r[rt], B2[kt & 1][nt], acc2[rt][nt], 0, 0, 0);
    }
#pragma unroll
    for (int rt = 0; rt < 2; ++rt) {
      float s[4] = {0.f,0.f,0.f,0.f}, s2[4] = {0.f,0.f,0.f,0.f};
#pragma unroll
      for (int nt = 0; nt < 8; ++nt)
#pragma unroll
        for (int r = 0; r < 4; ++r) { const float v = acc2[rt][nt][r]; s[r] += v; s2[r] += v * v; }
      float mu[4], rs[4];
#pragma unroll
      for (int r = 0; r < 4; ++r) {
        s[r] += __shfl_xor(s[r], 1); s2[r] += __shfl_xor(s2[r], 1);
        s[r] += __shfl_xor(s[r], 2); s2[r] += __shfl_xor(s2[r], 2);
        s[r] += __shfl_xor(s[r], 4); s2[r] += __shfl_xor(s2[r], 4);
        s[r] += __shfl_xor(s[r], 8); s2[r] += __shfl_xor(s2[r], 8);
        const float m = s[r] * (1.f / 128.f);
        mu[r] = m;
        rs[r] = rsqrtf(s2[r] * (1.f / 128.f) - m * m + 1e-5f);
      }
#pragma unroll
      for (int nt = 0; nt < 8; ++nt) {
        const int col = nt * 16 + c;
        const float gg = Pp[896 + col], bb = Pp[1024 + col];
#pragma unroll
        for (int r = 0; r < 4; ++r) {
          float v = (acc2[rt][nt][r] - mu[r]) * rs[r] * gg + bb;
          v = v * __builtin_amdgcn_rcpf(1.f + __expf(-v));
          h[(rt * 16 + 4 * q + r) * 136 + col] = (__bf16)v;
        }
      }
    }
  }

  // ================= Layer 3: 128 -> 64, LN+SiLU (full 16-frag burst) ========
  {
    bf16x8 B3[4][4];
#pragma unroll
    for (int kt = 0; kt < 4; ++kt)
#pragma unroll
      for (int nt = 0; nt < 4; ++nt)
        B3[kt][nt] = wsf[7168 + (kt * 4 + nt) * 64 + lane];
    f32x4 acc3[2][4];
#pragma unroll
    for (int nt = 0; nt < 4; ++nt) {
      const float bb = Pp[1152 + nt * 16 + c];
      f32x4 vv = {bb, bb, bb, bb};
      acc3[0][nt] = vv;
      acc3[1][nt] = vv;
    }
#pragma unroll
    for (int kt = 0; kt < 4; ++kt) {
      bf16x8 A3r[2];
#pragma unroll
      for (int rt = 0; rt < 2; ++rt)
        A3r[rt] = *(const bf16x8*)(h + (rt * 16 + c) * 136 + kt * 32 + q * 8);
#pragma unroll
      for (int nt = 0; nt < 4; ++nt)
#pragma unroll
        for (int rt = 0; rt < 2; ++rt)
          acc3[rt][nt] = __builtin_amdgcn_mfma_f32_16x16x32_bf16(A3r[rt], B3[kt][nt], acc3[rt][nt], 0, 0, 0);
    }
#pragma unroll
    for (int rt = 0; rt < 2; ++rt) {
      float s[4] = {0.f,0.f,0.f,0.f}, s2[4] = {0.f,0.f,0.f,0.f};
#pragma unroll
      for (int nt = 0; nt < 4; ++nt)
#pragma unroll
        for (int r = 0; r < 4; ++r) { const float v = acc3[rt][nt][r]; s[r] += v; s2[r] += v * v; }
      float mu[4], rs[4];
#pragma unroll
      for (int r = 0; r < 4; ++r) {
        s[r] += __shfl_xor(s[r], 1); s2[r] += __shfl_xor(s2[r], 1);
        s[r] += __shfl_xor(s[r], 2); s2[r] += __shfl_xor(s2[r], 2);
        s[r] += __shfl_xor(s[r], 4); s2[r] += __shfl_xor(s2[r], 4);
        s[r] += __shfl_xor(s[r], 8); s2[r] += __shfl_xor(s2[r], 8);
        const float m = s[r] * (1.f / 64.f);
        mu[r] = m;
        rs[r] = rsqrtf(s2[r] * (1.f / 64.f) - m * m + 1e-5f);
      }
#pragma unroll
      for (int nt = 0; nt < 4; ++nt) {
        const int col = nt * 16 + c;
        const float gg = Pp[1216 + col], bb = Pp[1280 + col];
#pragma unroll
        for (int r = 0; r < 4; ++r) {
          float v = (acc3[rt][nt][r] - mu[r]) * rs[r] * gg + bb;
          v = v * __builtin_amdgcn_rcpf(1.f + __expf(-v));
          h[(rt * 16 + 4 * q + r) * 72 + col] = (__bf16)v;
        }
      }
    }
  }

  // ================= Layer 4 (101 cols) + softmax + projection ===============
  {
    bf16x8 B4[2][7];
#pragma unroll
    for (int kt = 0; kt < 2; ++kt)
#pragma unroll
      for (int nt = 0; nt < 7; ++nt)
        B4[kt][nt] = wsf[8192 + (kt * 8 + nt) * 64 + lane];
    bf16x8 A4f[2][2];
#pragma unroll
    for (int rt = 0; rt < 2; ++rt)
#pragma unroll
      for (int kt = 0; kt < 2; ++kt)
        A4f[rt][kt] = *(const bf16x8*)(h + (rt * 16 + c) * 72 + kt * 32 + q * 8);

    // Fence, then zero proj (proj [1152,4384) overlays only dead h1/h2 region;
    // live h3 [0,1152) disjoint; keep stores ordered after the A4f reads).
    asm volatile("" ::: "memory");
    {
      f32x4 z = {0.f, 0.f, 0.f, 0.f};
      f32x4* p4 = (f32x4*)proj;
      for (int i = lane; i < 808; i += 64) p4[i] = z;
    }

    f32x4 a4[2][7];
#pragma unroll
    for (int nt = 0; nt < 7; ++nt) {
      const float bb = Pp[1344 + nt * 16 + c];
      f32x4 vv = {bb, bb, bb, bb};
      a4[0][nt] = vv;
      a4[1][nt] = vv;
    }
#pragma unroll
    for (int kt = 0; kt < 2; ++kt)
#pragma unroll
      for (int nt = 0; nt < 7; ++nt)
#pragma unroll
        for (int rt = 0; rt < 2; ++rt)
          a4[rt][nt] = __builtin_amdgcn_mfma_f32_16x16x32_bf16(A4f[rt][kt], B4[kt][nt], a4[rt][nt], 0, 0, 0);

#pragma unroll
    for (int rt = 0; rt < 2; ++rt) {
      // softmax over 101 atoms per row, fully in-register
      float mx4[4] = {-3.4e38f, -3.4e38f, -3.4e38f, -3.4e38f};
#pragma unroll
      for (int nt = 0; nt < 7; ++nt) {
        const bool ok = (nt < 6) | (c < 5);
#pragma unroll
        for (int r = 0; r < 4; ++r)
          if (ok) mx4[r] = fmaxf(mx4[r], a4[rt][nt][r]);
      }
#pragma unroll
      for (int r = 0; r < 4; ++r) {
        mx4[r] = fmaxf(mx4[r], __shfl_xor(mx4[r], 1));
        mx4[r] = fmaxf(mx4[r], __shfl_xor(mx4[r], 2));
        mx4[r] = fmaxf(mx4[r], __shfl_xor(mx4[r], 4));
        mx4[r] = fmaxf(mx4[r], __shfl_xor(mx4[r], 8));
      }
      float sm4[4] = {0.f, 0.f, 0.f, 0.f};
#pragma unroll
      for (int nt = 0; nt < 7; ++nt) {
        const bool ok = (nt < 6) | (c < 5);
#pragma unroll
        for (int r = 0; r < 4; ++r) {
          const float e = ok ? __expf(a4[rt][nt][r] - mx4[r]) : 0.f;
          a4[rt][nt][r] = e;
          sm4[r] += e;
        }
      }
      float inv4[4];
#pragma unroll
      for (int r = 0; r < 4; ++r) {
        float s = sm4[r];
        s += __shfl_xor(s, 1);
        s += __shfl_xor(s, 2);
        s += __shfl_xor(s, 4);
        s += __shfl_xor(s, 8);
        inv4[r] = __builtin_amdgcn_rcpf(s);
      }

      const f32x4 rw4 = *(const f32x4*)(rew  + row0w + rt * 16 + 4 * q);
      const f32x4 bo4 = *(const f32x4*)(boot + row0w + rt * 16 + 4 * q);
      const f32x4 di4 = *(const f32x4*)(disc + row0w + rt * 16 + 4 * q);
      float bd[4];
#pragma unroll
      for (int r = 0; r < 4; ++r) bd[r] = bo4[r] * di4[r];

      // categorical projection: wave-private LDS atomics
#pragma unroll
      for (int nt = 0; nt < 7; ++nt) {
        const int col = nt * 16 + c;
        if ((nt < 6) | (c < 5)) {
          const float qsv = Pp[1472 + col];
#pragma unroll
          for (int r = 0; r < 4; ++r) {
            const float p = a4[rt][nt][r] * inv4[r];
            float tz = rw4[r] + bd[r] * qsv;
            tz = fminf(fmaxf(tz, -10.f), 10.f);
            const float b_ = (tz + 10.f) * 5.f;
            const float fl = floorf(b_), cl = ceilf(b_);
            int li = (int)fl, ui = (int)cl;
            if (ui == li) { if (li > 0) --li; else ++ui; }
            const int rb = (rt * 16 + 4 * q + r) * 101;
            atomicAdd(&proj[rb + li], p * ((float)ui - b_));
            atomicAdd(&proj[rb + ui], p * (b_ - (float)li));
          }
        }
      }
    }
  }

  // ---- coalesced float4 writeout of this wave's 32x101 block
  {
    const f32x4* p4 = (const f32x4*)proj;
    f32x4* o4 = (f32x4*)(out + (size_t)row0w * 101);
    for (int i = lane; i < 808; i += 64) o4[i] = p4[i];
  }
}

extern "C" void kernel_launch(void* const* d_in, const int* in_sizes, int n_in,
                              void* d_out, int out_size, void* d_ws, size_t ws_size,
                              hipStream_t stream)
{
  const int B = in_sizes[2];  // rewards: B elements
  __bf16* ws = (__bf16*)d_ws; // 153856 B used

  conv_weights<<<dim3(37), dim3(256), 0, stream>>>(
      (const float*)d_in[6],  (const float*)d_in[10], (const float*)d_in[14],
      (const float*)d_in[18],
      (const float*)d_in[7],  (const float*)d_in[8],  (const float*)d_in[9],
      (const float*)d_in[11], (const float*)d_in[12], (const float*)d_in[13],
      (const float*)d_in[15], (const float*)d_in[16], (const float*)d_in[17],
      (const float*)d_in[19], (const float*)d_in[5],  ws);

  sacq_wave<<<dim3(B / 128), dim3(256), 0, stream>>>(
      (const float*)d_in[0],  (const float*)d_in[1],  (const float*)d_in[2],
      (const float*)d_in[3],  (const float*)d_in[4],  (const float*)d_in[5],
      (const float*)d_in[7],  (const float*)d_in[8],  (const float*)d_in[9],
      (const float*)d_in[11], (const float*)d_in[12], (const float*)d_in[13],
      (const float*)d_in[15], (const float*)d_in[16], (const float*)d_in[17],
      (const float*)d_in[19], ws, (float*)d_out);
}

// Round 6
// 309.676 us; speedup vs baseline: 1.1138x; 1.0743x over previous
//
#include <hip/hip_runtime.h>
#include <math.h>

typedef __bf16 bf16x8 __attribute__((ext_vector_type(8)));
typedef __bf16 bf16x4 __attribute__((ext_vector_type(4)));
typedef float f32x4 __attribute__((ext_vector_type(4)));

// ---------------- weight conversion: fp32 -> bf16 frag-major in d_ws ----------
// Frag (kt,nt) = 32x16 block of B; lane L holds B[kt*32+(L>>4)*8+j][nt*16+(L&15)],
// j=0..7 -> one 16B chunk at L*16. Offsets (bf16 units): L1@0 (96x256, 48 frags),
// L2@24576 (256x128, 64), L3@57344 (128x64, 16), L4@65536 (64x128, 16; N 101->128 pad).
// Params packed LINEAR f32 at bf16-offset 73728 (quad index = float/4):
//   0..255 b1 | 256..511 g1 | 512..767 be1 | 768..895 b2 | 896..1023 g2
//   1024..1151 be2 | 1152..1215 b3 | 1216..1279 g3 | 1280..1343 be3
//   1344..1471 b4 (pad 0) | 1472..1599 qsup (pad 0).  Total ws: 153856 B.
__global__ void conv_weights(const float* __restrict__ W1, const float* __restrict__ W2,
                             const float* __restrict__ W3, const float* __restrict__ W4,
                             const float* __restrict__ b1, const float* __restrict__ g1, const float* __restrict__ be1,
                             const float* __restrict__ b2, const float* __restrict__ g2, const float* __restrict__ be2,
                             const float* __restrict__ b3, const float* __restrict__ g3, const float* __restrict__ be3,
                             const float* __restrict__ b4, const float* __restrict__ qsup,
                             __bf16* __restrict__ ws)
{
  if (blockIdx.x == 36) {
    float* Pp = (float*)(ws + 73728);
    const int t = threadIdx.x;
    Pp[t]       = b1[t];
    Pp[256 + t] = g1[t];
    Pp[512 + t] = be1[t];
    if (t < 128) {
      Pp[768 + t]  = b2[t];
      Pp[896 + t]  = g2[t];
      Pp[1024 + t] = be2[t];
      Pp[1344 + t] = (t < 101) ? b4[t]   : 0.f;
      Pp[1472 + t] = (t < 101) ? qsup[t] : 0.f;
    }
    if (t < 64) {
      Pp[1152 + t] = b3[t];
      Pp[1216 + t] = g3[t];
      Pp[1280 + t] = be3[t];
    }
    return;
  }
  const int f = blockIdx.x * 4 + (threadIdx.x >> 6);
  const int lane = threadIdx.x & 63;
  int f0, ntot, Ksrc, Nsrc, off;
  const float* W;
  if (f < 48)       { f0 = f;       ntot = 16; Ksrc = 80;  Nsrc = 256; W = W1; off = 0; }
  else if (f < 112) { f0 = f - 48;  ntot = 8;  Ksrc = 256; Nsrc = 128; W = W2; off = 24576; }
  else if (f < 128) { f0 = f - 112; ntot = 4;  Ksrc = 128; Nsrc = 64;  W = W3; off = 57344; }
  else              { f0 = f - 128; ntot = 8;  Ksrc = 64;  Nsrc = 101; W = W4; off = 65536; }
  const int kt = f0 / ntot, nt = f0 % ntot;
  const int q = lane >> 4, c = lane & 15;
  const int n = nt * 16 + c;
  bf16x8 v;
#pragma unroll
  for (int j = 0; j < 8; ++j) {
    const int k = kt * 32 + q * 8 + j;
    const float x = (k < Ksrc && n < Nsrc) ? W[k * Nsrc + n] : 0.f;
    v[j] = (__bf16)x;
  }
  ((bf16x8*)(ws + off))[f0 * 64 + lane] = v;
}

// ---------------- fused forward: operand-swapped MFMA (out^T), 32 rows/wave ---
// THIS ROUND: pass the ws weight fragment as the A operand and the activation
// fragment as B (fragment layouts are A/B-symmetric, so ws layout and all h
// reads are unchanged). The C layout flips to out^T[feature][batch]: each
// lane's 4 acc regs = 4 CONSECUTIVE FEATURES of one batch row (col c). That
// makes (a) LN/softmax stats lane-local + 2 shfl (was 4-16 shfl chains),
// (b) epilogue stores one bf16x4 (8B) per 4 values (was 4 cvt + 4 b16 writes),
// (c) per-feature params f32x4-loadable at P4[base + 4*mt + q].
// Projection rewritten branch-free: li=min(floor(b),99), uw=p*frac, lw=p-uw
// (provably equals the reference's integer-case handling; indices in [0,100]).
//
// Per-wave LDS (floats, stride 4384):
//   h1 [32][264] bf16 = floats [0,4224) (h2 [32][136], h3 [32][72] overlay;
//      layer-k writes ordered after layer-(k-1) reads: alias-conservative
//      compiler order + in-order per-wave DS)
//   proj [32][101] = floats [1152,4384)  (L4 only; h3 [0,1152) disjoint)
// Block = 4*4384*4 = 70144 B -> 2 blocks/CU. Grid B/128 = 1024.

__global__ __launch_bounds__(256, 2)
void sacq_wave(const float* __restrict__ obs,  const float* __restrict__ act,
               const float* __restrict__ rew,  const float* __restrict__ boot,
               const float* __restrict__ disc, const float* __restrict__ qsup,
               const float* __restrict__ b1, const float* __restrict__ g1, const float* __restrict__ be1,
               const float* __restrict__ b2, const float* __restrict__ g2, const float* __restrict__ be2,
               const float* __restrict__ b3, const float* __restrict__ g3, const float* __restrict__ be3,
               const float* __restrict__ b4,
               const __bf16* __restrict__ ws,
               float* __restrict__ out)
{
  __shared__ float sm[17536];
  const int t = threadIdx.x;
  const int wv = t >> 6, lane = t & 63;
  const int q = lane >> 4, c = lane & 15;
  float* smw = sm + wv * 4384;
  __bf16* h = (__bf16*)smw;               // h1/h2/h3 overlay
  float* proj = smw + 1152;               // [32][101] (L4 only)
  const int row0w = blockIdx.x * 128 + wv * 32;
  const bf16x8* wsf = (const bf16x8*)ws;
  const f32x4* P4 = (const f32x4*)(const void*)(ws + 73728);
  const int fq = 4 * q;                   // feature sub-offset within an m-tile

  // ================= Layer 1: out^T[256][32] = W1^T @ x^T, LN+SiLU ==========
  f32x4 acc1[2][16];
  {
    bf16x8 A1[2][3];   // activation fragments (B operand): lane c holds row c
#pragma unroll
    for (int rt = 0; rt < 2; ++rt) {
      const float4* ob4 = (const float4*)(obs + (size_t)(row0w + rt * 16 + c) * 60);
      const float4* ac4 = (const float4*)(act + (size_t)(row0w + rt * 16 + c) * 20);
#pragma unroll
      for (int kt = 0; kt < 3; ++kt) {
        const int k0 = kt * 32 + q * 8;
        float v[8];
        if (k0 < 56) {
          const float4 a = ob4[k0 / 4], b = ob4[k0 / 4 + 1];
          v[0]=a.x; v[1]=a.y; v[2]=a.z; v[3]=a.w; v[4]=b.x; v[5]=b.y; v[6]=b.z; v[7]=b.w;
        } else if (k0 == 56) {
          const float4 a = ob4[14], b = ac4[0];
          v[0]=a.x; v[1]=a.y; v[2]=a.z; v[3]=a.w; v[4]=b.x; v[5]=b.y; v[6]=b.z; v[7]=b.w;
        } else if (k0 < 80) {
          const float4 a = ac4[(k0 - 60) / 4], b = ac4[(k0 - 60) / 4 + 1];
          v[0]=a.x; v[1]=a.y; v[2]=a.z; v[3]=a.w; v[4]=b.x; v[5]=b.y; v[6]=b.z; v[7]=b.w;
        } else {
#pragma unroll
          for (int j = 0; j < 8; ++j) v[j] = 0.f;
        }
#pragma unroll
        for (int j = 0; j < 8; ++j) A1[rt][kt][j] = (__bf16)v[j];
      }
    }
    // acc init with bias: acc[rt][mt][r] = b1[16mt+4q+r] -> one f32x4 per mt
#pragma unroll
    for (int mt = 0; mt < 16; ++mt) {
      const f32x4 pb = P4[4 * mt + q];
      acc1[0][mt] = pb;
      acc1[1][mt] = pb;
    }
    // 4 chunks of 4 m-tiles; each chunk: 12 W-frag loads, then 24 MFMAs
#pragma unroll
    for (int ch = 0; ch < 4; ++ch) {
      bf16x8 Wb[3][4];
#pragma unroll
      for (int kt = 0; kt < 3; ++kt)
#pragma unroll
        for (int j = 0; j < 4; ++j)
          Wb[kt][j] = wsf[(kt * 16 + ch * 4 + j) * 64 + lane];
#pragma unroll
      for (int kt = 0; kt < 3; ++kt)
#pragma unroll
        for (int j = 0; j < 4; ++j)
#pragma unroll
          for (int rt = 0; rt < 2; ++rt)
            acc1[rt][ch * 4 + j] = __builtin_amdgcn_mfma_f32_16x16x32_bf16(Wb[kt][j], A1[rt][kt], acc1[rt][ch * 4 + j], 0, 0, 0);
    }
    // LN stats: lane-local over 64 features + butterfly over q-lanes (2 shfl)
#pragma unroll
    for (int rt = 0; rt < 2; ++rt) {
      float s = 0.f, s2 = 0.f;
#pragma unroll
      for (int mt = 0; mt < 16; ++mt)
#pragma unroll
        for (int r = 0; r < 4; ++r) { const float v = acc1[rt][mt][r]; s += v; s2 += v * v; }
      s += __shfl_xor(s, 16); s2 += __shfl_xor(s2, 16);
      s += __shfl_xor(s, 32); s2 += __shfl_xor(s2, 32);
      const float mu = s * (1.f / 256.f);
      const float rs = rsqrtf(s2 * (1.f / 256.f) - mu * mu + 1e-5f);
#pragma unroll
      for (int mt = 0; mt < 16; ++mt) {
        const f32x4 g4  = P4[64 + 4 * mt + q];
        const f32x4 be4 = P4[128 + 4 * mt + q];
        bf16x4 o;
#pragma unroll
        for (int r = 0; r < 4; ++r) {
          float x = (acc1[rt][mt][r] - mu) * rs * g4[r] + be4[r];
          x = x * __builtin_amdgcn_rcpf(1.f + __expf(-x));
          o[r] = (__bf16)x;
        }
        *(bf16x4*)(h + (rt * 16 + c) * 264 + 16 * mt + fq) = o;
      }
    }
  }

  // ================= Layer 2: out^T[128][32] = W2^T @ h1^T, LN+SiLU =========
  {
    f32x4 acc2[2][8];
#pragma unroll
    for (int mt = 0; mt < 8; ++mt) {
      const f32x4 pb = P4[192 + 4 * mt + q];
      acc2[0][mt] = pb;
      acc2[1][mt] = pb;
    }
    bf16x8 W2f[2][8];
#pragma unroll
    for (int mt = 0; mt < 8; ++mt) W2f[0][mt] = wsf[3072 + mt * 64 + lane];
#pragma unroll
    for (int kt = 0; kt < 8; ++kt) {
      if (kt + 1 < 8) {
#pragma unroll
        for (int mt = 0; mt < 8; ++mt)
          W2f[(kt + 1) & 1][mt] = wsf[3072 + ((kt + 1) * 8 + mt) * 64 + lane];
      }
      bf16x8 A2r[2];
#pragma unroll
      for (int rt = 0; rt < 2; ++rt)
        A2r[rt] = *(const bf16x8*)(h + (rt * 16 + c) * 264 + kt * 32 + q * 8);
#pragma unroll
      for (int mt = 0; mt < 8; ++mt)
#pragma unroll
        for (int rt = 0; rt < 2; ++rt)
          acc2[rt][mt] = __builtin_amdgcn_mfma_f32_16x16x32_bf16(W2f[kt & 1][mt], A2r[rt], acc2[rt][mt], 0, 0, 0);
    }
#pragma unroll
    for (int rt = 0; rt < 2; ++rt) {
      float s = 0.f, s2 = 0.f;
#pragma unroll
      for (int mt = 0; mt < 8; ++mt)
#pragma unroll
        for (int r = 0; r < 4; ++r) { const float v = acc2[rt][mt][r]; s += v; s2 += v * v; }
      s += __shfl_xor(s, 16); s2 += __shfl_xor(s2, 16);
      s += __shfl_xor(s, 32); s2 += __shfl_xor(s2, 32);
      const float mu = s * (1.f / 128.f);
      const float rs = rsqrtf(s2 * (1.f / 128.f) - mu * mu + 1e-5f);
#pragma unroll
      for (int mt = 0; mt < 8; ++mt) {
        const f32x4 g4  = P4[224 + 4 * mt + q];
        const f32x4 be4 = P4[256 + 4 * mt + q];
        bf16x4 o;
#pragma unroll
        for (int r = 0; r < 4; ++r) {
          float x = (acc2[rt][mt][r] - mu) * rs * g4[r] + be4[r];
          x = x * __builtin_amdgcn_rcpf(1.f + __expf(-x));
          o[r] = (__bf16)x;
        }
        *(bf16x4*)(h + (rt * 16 + c) * 136 + 16 * mt + fq) = o;
      }
    }
  }

  // ================= Layer 3: out^T[64][32] = W3^T @ h2^T, LN+SiLU ==========
  {
    bf16x8 W3f[4][4];
#pragma unroll
    for (int kt = 0; kt < 4; ++kt)
#pragma unroll
      for (int mt = 0; mt < 4; ++mt)
        W3f[kt][mt] = wsf[7168 + (kt * 4 + mt) * 64 + lane];
    f32x4 acc3[2][4];
#pragma unroll
    for (int mt = 0; mt < 4; ++mt) {
      const f32x4 pb = P4[288 + 4 * mt + q];
      acc3[0][mt] = pb;
      acc3[1][mt] = pb;
    }
#pragma unroll
    for (int kt = 0; kt < 4; ++kt) {
      bf16x8 A3r[2];
#pragma unroll
      for (int rt = 0; rt < 2; ++rt)
        A3r[rt] = *(const bf16x8*)(h + (rt * 16 + c) * 136 + kt * 32 + q * 8);
#pragma unroll
      for (int mt = 0; mt < 4; ++mt)
#pragma unroll
        for (int rt = 0; rt < 2; ++rt)
          acc3[rt][mt] = __builtin_amdgcn_mfma_f32_16x16x32_bf16(W3f[kt][mt], A3r[rt], acc3[rt][mt], 0, 0, 0);
    }
#pragma unroll
    for (int rt = 0; rt < 2; ++rt) {
      float s = 0.f, s2 = 0.f;
#pragma unroll
      for (int mt = 0; mt < 4; ++mt)
#pragma unroll
        for (int r = 0; r < 4; ++r) { const float v = acc3[rt][mt][r]; s += v; s2 += v * v; }
      s += __shfl_xor(s, 16); s2 += __shfl_xor(s2, 16);
      s += __shfl_xor(s, 32); s2 += __shfl_xor(s2, 32);
      const float mu = s * (1.f / 64.f);
      const float rs = rsqrtf(s2 * (1.f / 64.f) - mu * mu + 1e-5f);
#pragma unroll
      for (int mt = 0; mt < 4; ++mt) {
        const f32x4 g4  = P4[304 + 4 * mt + q];
        const f32x4 be4 = P4[320 + 4 * mt + q];
        bf16x4 o;
#pragma unroll
        for (int r = 0; r < 4; ++r) {
          float x = (acc3[rt][mt][r] - mu) * rs * g4[r] + be4[r];
          x = x * __builtin_amdgcn_rcpf(1.f + __expf(-x));
          o[r] = (__bf16)x;
        }
        *(bf16x4*)(h + (rt * 16 + c) * 72 + 16 * mt + fq) = o;
      }
    }
  }

  // ================= Layer 4 (101 feats) + softmax + projection =============
  {
    bf16x8 W4f[2][7];
#pragma unroll
    for (int kt = 0; kt < 2; ++kt)
#pragma unroll
      for (int mt = 0; mt < 7; ++mt)
        W4f[kt][mt] = wsf[8192 + (kt * 8 + mt) * 64 + lane];
    bf16x8 A4f[2][2];
#pragma unroll
    for (int rt = 0; rt < 2; ++rt)
#pragma unroll
      for (int kt = 0; kt < 2; ++kt)
        A4f[rt][kt] = *(const bf16x8*)(h + (rt * 16 + c) * 72 + kt * 32 + q * 8);

    // Fence, then zero proj (proj [1152,4384) overlays only dead h1/h2 region;
    // live h3 [0,1152) disjoint; keep stores ordered after the A4f reads).
    asm volatile("" ::: "memory");
    {
      f32x4 z = {0.f, 0.f, 0.f, 0.f};
      f32x4* p4 = (f32x4*)proj;
      for (int i = lane; i < 808; i += 64) p4[i] = z;
    }

    f32x4 a4[2][7];
#pragma unroll
    for (int mt = 0; mt < 7; ++mt) {
      const f32x4 pb = P4[336 + 4 * mt + q];
      a4[0][mt] = pb;
      a4[1][mt] = pb;
    }
#pragma unroll
    for (int kt = 0; kt < 2; ++kt)
#pragma unroll
      for (int mt = 0; mt < 7; ++mt)
#pragma unroll
        for (int rt = 0; rt < 2; ++rt)
          a4[rt][mt] = __builtin_amdgcn_mfma_f32_16x16x32_bf16(W4f[kt][mt], A4f[rt][kt], a4[rt][mt], 0, 0, 0);

#pragma unroll
    for (int rt = 0; rt < 2; ++rt) {
      // softmax over the 101 features of this lane's batch row (lane-local + 2 shfl)
      float mx = -3.4e38f;
#pragma unroll
      for (int mt = 0; mt < 7; ++mt) {
#pragma unroll
        for (int r = 0; r < 4; ++r) {
          const bool ok = (mt < 6) | (fq + r < 5);
          if (ok) mx = fmaxf(mx, a4[rt][mt][r]);
        }
      }
      mx = fmaxf(mx, __shfl_xor(mx, 16));
      mx = fmaxf(mx, __shfl_xor(mx, 32));
      float sp = 0.f;
#pragma unroll
      for (int mt = 0; mt < 7; ++mt) {
#pragma unroll
        for (int r = 0; r < 4; ++r) {
          const bool ok = (mt < 6) | (fq + r < 5);
          const float e = ok ? __expf(a4[rt][mt][r] - mx) : 0.f;
          a4[rt][mt][r] = e;
          sp += e;
        }
      }
      sp += __shfl_xor(sp, 16);
      sp += __shfl_xor(sp, 32);
      const float inv = __builtin_amdgcn_rcpf(sp);

      const int gr = row0w + rt * 16 + c;
      const float rw = rew[gr];
      const float bd = boot[gr] * disc[gr];
      const int rb = (rt * 16 + c) * 101;

      // categorical projection (branch-free index math; li in [0,99])
#pragma unroll
      for (int mt = 0; mt < 7; ++mt) {
        const f32x4 qs4 = P4[368 + 4 * mt + q];
#pragma unroll
        for (int r = 0; r < 4; ++r) {
          const bool ok = (mt < 6) | (fq + r < 5);
          if (ok) {
            const float p = a4[rt][mt][r] * inv;
            float tz = rw + bd * qs4[r];
            tz = fminf(fmaxf(tz, -10.f), 10.f);
            const float b_ = tz * 5.f + 50.f;            // in [0,100]
            const float fl = fminf(floorf(b_), 99.f);    // in [0,99]
            const float frac = b_ - fl;                  // in [0,1]
            const float uw = p * frac;
            const float lw = p - uw;
            const int li = (int)fl;
            atomicAdd(&proj[rb + li], lw);
            atomicAdd(&proj[rb + li + 1], uw);
          }
        }
      }
    }
  }

  // ---- coalesced float4 writeout of this wave's 32x101 block
  {
    const f32x4* p4 = (const f32x4*)proj;
    f32x4* o4 = (f32x4*)(out + (size_t)row0w * 101);
    for (int i = lane; i < 808; i += 64) o4[i] = p4[i];
  }
}

extern "C" void kernel_launch(void* const* d_in, const int* in_sizes, int n_in,
                              void* d_out, int out_size, void* d_ws, size_t ws_size,
                              hipStream_t stream)
{
  const int B = in_sizes[2];  // rewards: B elements
  __bf16* ws = (__bf16*)d_ws; // 153856 B used

  conv_weights<<<dim3(37), dim3(256), 0, stream>>>(
      (const float*)d_in[6],  (const float*)d_in[10], (const float*)d_in[14],
      (const float*)d_in[18],
      (const float*)d_in[7],  (const float*)d_in[8],  (const float*)d_in[9],
      (const float*)d_in[11], (const float*)d_in[12], (const float*)d_in[13],
      (const float*)d_in[15], (const float*)d_in[16], (const float*)d_in[17],
      (const float*)d_in[19], (const float*)d_in[5],  ws);

  sacq_wave<<<dim3(B / 128), dim3(256), 0, stream>>>(
      (const float*)d_in[0],  (const float*)d_in[1],  (const float*)d_in[2],
      (const float*)d_in[3],  (const float*)d_in[4],  (const float*)d_in[5],
      (const float*)d_in[7],  (const float*)d_in[8],  (const float*)d_in[9],
      (const float*)d_in[11], (const float*)d_in[12], (const float*)d_in[13],
      (const float*)d_in[15], (const float*)d_in[16], (const float*)d_in[17],
      (const float*)d_in[19], ws, (float*)d_out);
}